// Round 11
// baseline (379.938 us; speedup 1.0000x reference)
//
#include <hip/hip_runtime.h>
#include <hip/hip_bf16.h>

#define B_ 8
#define C_ 2048
#define DIM_ 512
#define NEG_SLOPE 0.01f

typedef short bf16x8 __attribute__((ext_vector_type(8)));
typedef short bf16x4 __attribute__((ext_vector_type(4)));
typedef float f32x4 __attribute__((ext_vector_type(4)));

// ---- workspace byte offsets
#define WT_OFF   0                        // bf16 Wt[512][512] (W_comb^T)
#define UT_OFF   524288                   // bf16 Ut[8*512][2048]  (U^T per batch)
#define FP_OFF   (524288 + 16777216)      // fp32 region
// ---- float offsets inside fp32 region
#define BCOMB_F  0
#define WQ_F     512
#define WK_F     1024
#define CQB_F    1536
#define CK_F     1537
#define SQP_F    2048
#define SKP_F    18432

static __device__ __forceinline__ unsigned short bf16u(float x) {
    union { __hip_bfloat16 h; unsigned short u; } c;
    c.h = __float2bfloat16(x);
    return c.u;
}

// wq_vec[e] = sum_h W_w[e,h]*a[h]; wk_vec[e] = sum_h W_w[e,512+h]*a[512+h]
__global__ void k_prep_wqk(const float* __restrict__ W_w, const float* __restrict__ a_score, float* wsf) {
    int wave = threadIdx.x >> 6, lane = threadIdx.x & 63;
    int e = blockIdx.x * 4 + wave;
    const float4* R4 = (const float4*)(W_w + (size_t)e * 1536);
    const float4* A4 = (const float4*)a_score;
    float aq = 0.f, ak = 0.f;
#pragma unroll
    for (int k = 0; k < 2; ++k) {
        float4 f = R4[lane + 64 * k];
        float4 a = A4[lane + 64 * k];
        aq += f.x * a.x + f.y * a.y + f.z * a.z + f.w * a.w;
        float4 g = R4[128 + lane + 64 * k];
        float4 a2 = A4[128 + lane + 64 * k];
        ak += g.x * a2.x + g.y * a2.y + g.z * a2.z + g.w * a2.w;
    }
#pragma unroll
    for (int off = 32; off; off >>= 1) { aq += __shfl_xor(aq, off); ak += __shfl_xor(ak, off); }
    if (lane == 0) { wsf[WQ_F + e] = aq; wsf[WK_F + e] = ak; }
}

__global__ void k_prep_cqk(const float* __restrict__ b_w, const float* __restrict__ a_score,
                           const float* __restrict__ b_score, float* wsf) {
    __shared__ float s1[512], s2[512];
    int t = threadIdx.x;
    s1[t] = b_w[t] * a_score[t];
    s2[t] = b_w[512 + t] * a_score[512 + t];
    __syncthreads();
    for (int off = 256; off > 0; off >>= 1) {
        if (t < off) { s1[t] += s1[t + off]; s2[t] += s2[t + off]; }
        __syncthreads();
    }
    if (t == 0) { wsf[CQB_F] = s1[0] + b_score[0]; wsf[CK_F] = s2[0]; }
}

// Wt[d][e] = sum_h W_w[e,1024+h]*W_out[h,d]; bcomb[d] = sum_h b_w[1024+h]*W_out[h,d]
__global__ __launch_bounds__(256) void k_wt(const float* __restrict__ W_w,
                                            const float* __restrict__ W_out,
                                            const float* __restrict__ b_w,
                                            char* wsb, float* wsf) {
    __shared__ float As[32][34];
    __shared__ float Bs[32][34];
    const int t = threadIdx.x;
    const int d0 = (blockIdx.x & 15) * 32;
    const int e0 = (blockIdx.x >> 4) * 32;
    const int ty = t >> 4, tx = t & 15;
    const int hl = t >> 5, c = t & 31;
    float a00 = 0.f, a01 = 0.f, a10 = 0.f, a11 = 0.f;
    float bc = 0.f;
    for (int k0 = 0; k0 < 512; k0 += 32) {
#pragma unroll
        for (int r = 0; r < 4; ++r) {
            int h = hl + 8 * r;
            As[h][c] = W_out[(size_t)(k0 + h) * 512 + d0 + c];
            Bs[c][h] = W_w[(size_t)(e0 + h) * 1536 + 1024 + k0 + c];
        }
        __syncthreads();
        if (e0 == 0 && t < 32) {
#pragma unroll
            for (int kk = 0; kk < 32; ++kk)
                bc = fmaf(b_w[1024 + k0 + kk], As[kk][t], bc);
        }
#pragma unroll
        for (int kk = 0; kk < 32; ++kk) {
            float2 a2 = *(const float2*)&As[kk][ty * 2];
            float2 b2 = *(const float2*)&Bs[kk][tx * 2];
            a00 = fmaf(a2.x, b2.x, a00);
            a01 = fmaf(a2.x, b2.y, a01);
            a10 = fmaf(a2.y, b2.x, a10);
            a11 = fmaf(a2.y, b2.y, a11);
        }
        __syncthreads();
    }
    unsigned short* Wt = (unsigned short*)(wsb + WT_OFF);
    const int d = d0 + ty * 2, e = e0 + tx * 2;
    Wt[(size_t)d * 512 + e]           = bf16u(a00);
    Wt[(size_t)d * 512 + e + 1]       = bf16u(a01);
    Wt[(size_t)(d + 1) * 512 + e]     = bf16u(a10);
    Wt[(size_t)(d + 1) * 512 + e + 1] = bf16u(a11);
    if (e0 == 0 && t < 32) wsf[BCOMB_F + d0 + t] = bc;
}

// sq'[n], sk'[n]
__global__ void k_sqsk(const float* __restrict__ feat, float* wsf) {
    int wave = threadIdx.x >> 6, lane = threadIdx.x & 63;
    int n = blockIdx.x * 4 + wave;
    const float4* F4 = (const float4*)(feat + (size_t)n * 512);
    const float4* WQ4 = (const float4*)(wsf + WQ_F);
    const float4* WK4 = (const float4*)(wsf + WK_F);
    float aq = 0.f, ak = 0.f;
#pragma unroll
    for (int k = 0; k < 2; ++k) {
        float4 f = F4[lane + 64 * k];
        float4 q = WQ4[lane + 64 * k];
        float4 kk = WK4[lane + 64 * k];
        aq += f.x * q.x + f.y * q.y + f.z * q.z + f.w * q.w;
        ak += f.x * kk.x + f.y * kk.y + f.z * kk.z + f.w * kk.w;
    }
#pragma unroll
    for (int off = 32; off; off >>= 1) { aq += __shfl_xor(aq, off); ak += __shfl_xor(ak, off); }
    if (lane == 0) {
        wsf[SQP_F + n] = aq + wsf[CQB_F];
        wsf[SKP_F + n] = ak + wsf[CK_F];
    }
}

// Ut[b,d,j] = sum_e Wt[d,e] * F[b,j,e]   (512 blocks: j-tile 32, 4 waves x 128 d)
__global__ __launch_bounds__(256) void k_ut(const float* __restrict__ F, char* __restrict__ wsb) {
    __shared__ unsigned short Fb[32][520];
    const int t = threadIdx.x;
    const int bid = blockIdx.x;
    const int b = bid & 7, j0 = (bid >> 3) * 32;
    const unsigned short* Wt = (const unsigned short*)(wsb + WT_OFF);
    unsigned short* Ut = (unsigned short*)(wsb + UT_OFF) + (size_t)b * 512 * 2048;
    const float* Ft = F + ((size_t)(b * C_ + j0)) * 512;
#pragma unroll
    for (int q = 0; q < 16; ++q) {
        float4 v = *(const float4*)(Ft + (size_t)q * 1024 + t * 4);
        int jr = 2 * q + (t >> 7);
        int e = (t & 127) * 4;
        unsigned int lo = (unsigned int)bf16u(v.x) | ((unsigned int)bf16u(v.y) << 16);
        unsigned int hi = (unsigned int)bf16u(v.z) | ((unsigned int)bf16u(v.w) << 16);
        *(uint2*)&Fb[jr][e] = make_uint2(lo, hi);
    }
    __syncthreads();
    const int l = t & 63, lr = l & 15, lg = l >> 4;
    const int d0 = (t >> 6) * 128;
    f32x4 acc[8][2];
#pragma unroll
    for (int m = 0; m < 8; ++m)
#pragma unroll
        for (int n = 0; n < 2; ++n) acc[m][n] = (f32x4){0.f, 0.f, 0.f, 0.f};
#pragma unroll
    for (int ks = 0; ks < 16; ++ks) {
        bf16x8 af[8], bv[2];
#pragma unroll
        for (int m = 0; m < 8; ++m)
            af[m] = *(const bf16x8*)(Wt + (size_t)(d0 + 16 * m + lr) * 512 + ks * 32 + 8 * lg);
#pragma unroll
        for (int n = 0; n < 2; ++n)
            bv[n] = *(const bf16x8*)&Fb[16 * n + lr][ks * 32 + 8 * lg];
#pragma unroll
        for (int m = 0; m < 8; ++m)
#pragma unroll
            for (int n = 0; n < 2; ++n)
                acc[m][n] = __builtin_amdgcn_mfma_f32_16x16x32_bf16(af[m], bv[n], acc[m][n], 0, 0, 0);
    }
#pragma unroll
    for (int m = 0; m < 8; ++m)
#pragma unroll
        for (int n = 0; n < 2; ++n)
#pragma unroll
            for (int r = 0; r < 4; ++r) {
                int d = d0 + 16 * m + lg * 4 + r;
                int j = j0 + 16 * n + lr;
                Ut[(size_t)d * 2048 + j] = bf16u(acc[m][n][r]);
            }
}

// -------- fused attention, counted-vmcnt pipeline, 2 independent blocks/CU --------
// 512 blocks x 512 thr (8 waves). Block: batch b, 32 i-rows, k-step 64.
// Wave w owns d-slice [w*64, +64). P tile [2][32][64] bf16 LDS, XOR-swizzled
// 16B units; P computed once: thread t -> row t>>4, cols (t&15)*4.
// Mask depth-3 reg slots, Ut depth-1. Phase barrier: lgkmcnt(0)+s_barrier only.
// 2 blocks/CU = independent barrier groups: one block's barrier convergence
// overlaps the other's compute (m114 mechanism).

#define BAR asm volatile("s_waitcnt lgkmcnt(0)\n\ts_barrier" ::: "memory");
#define SCHEDB __builtin_amdgcn_sched_barrier(0);

#define MISSUE(M, KT) { \
    M = __builtin_nontemporal_load((const f32x4*)(mrow + (size_t)(KT) * 64)); }

#define PCX(KV, MV, I) { \
    float z = sqv + (KV); z = fmaxf(z, z * NEG_SLOPE) * (MV); \
    z = __expf(z); psum += z; vv[I] = (short)bf16u(z); }

#define PCOMP(M, KT) { \
    const int kt = (KT); \
    float4 ka = *(const float4*)&sk_lds[kt * 64 + pjc * 4]; \
    bf16x4 vv; \
    PCX(ka.x, M[0], 0) PCX(ka.y, M[1], 1) PCX(ka.z, M[2], 2) PCX(ka.w, M[3], 3) \
    *(bf16x4*)(Pbyte + (kt & 1) * 4096 + prow * 128 \
               + (((pjc >> 1) ^ (prow & 7)) << 4) + ((pjc & 1) << 3)) = vv; }

#define LDUT(U, KT) { \
    const int kt = (KT); \
    _Pragma("unroll") \
    for (int n = 0; n < 4; ++n) { \
        const unsigned short* up = Utw + (size_t)(16 * n + lr) * 2048 + kt * 64 + 8 * lg; \
        U[2 * n]     = *(const bf16x8*)up; \
        U[2 * n + 1] = *(const bf16x8*)(up + 32); \
    } }

#define MFMAP(U, KP) { \
    const char* pb = Pbyte + ((KP) & 1) * 4096; \
    _Pragma("unroll") \
    for (int g = 0; g < 2; ++g) { \
        const char* rp = pb + (16 * g + lr) * 128; \
        bf16x8 a0 = *(const bf16x8*)(rp + ((lg ^ (lr & 7)) << 4)); \
        bf16x8 a1 = *(const bf16x8*)(rp + (((4 + lg) ^ (lr & 7)) << 4)); \
        _Pragma("unroll") \
        for (int n = 0; n < 4; ++n) { \
            acc[g][n] = __builtin_amdgcn_mfma_f32_16x16x32_bf16(a0, U[2 * n],     acc[g][n], 0, 0, 0); \
            acc[g][n] = __builtin_amdgcn_mfma_f32_16x16x32_bf16(a1, U[2 * n + 1], acc[g][n], 0, 0, 0); \
        } \
    } }

#define PHASE(UC, UN, MC, MI, KP) { \
    const int kp = (KP); \
    if (kp + 1 < 32) { PCOMP(MC, kp + 1) LDUT(UN, kp + 1) } \
    SCHEDB \
    if (kp + 3 < 32) MISSUE(MI, kp + 3) \
    SCHEDB \
    MFMAP(UC, kp) \
    BAR }

__global__ __launch_bounds__(512, 4) void k_attn(const float* __restrict__ mask,
                                                 const float* __restrict__ b_out,
                                                 char* __restrict__ wsb,
                                                 float* __restrict__ out) {
    __shared__ unsigned short Pt[2][32][64];
    __shared__ float sk_lds[2048];
    __shared__ float bcbo[512];
    __shared__ float psums[32][16];
    __shared__ float rinvs[32];
    const int t = threadIdx.x;
    const int bid = blockIdx.x;
    const int b = bid & 7, i0 = (bid >> 3) * 32;      // b -> XCD; Ut[b] L2-resident
    const int w = t >> 6, l = t & 63, lr = l & 15, lg = l >> 4;
    const int prow = t >> 4, pjc = t & 15;            // P-compute coords
    const float* wsf = (const float*)(wsb + FP_OFF);
    const unsigned short* Utw = (const unsigned short*)(wsb + UT_OFF)
                                + (size_t)b * 512 * 2048 + (size_t)(w * 64) * 2048;
    char* Pbyte = (char*)Pt;
    const float sqv = wsf[SQP_F + b * C_ + i0 + prow];
    const float* mrow = mask + ((size_t)(b * C_ + i0 + prow)) * C_ + pjc * 4;

    {   // stage sk row + fused bias
        const float* skp = wsf + SKP_F + b * C_;
        *(float4*)&sk_lds[t * 4] = *(const float4*)(skp + t * 4);
        bcbo[t & 511] = wsf[BCOMB_F + (t & 511)] + b_out[t & 511];
    }
    __syncthreads();

    f32x4 m0, m1, m2;
    bf16x8 u0[8], u1[8];
    MISSUE(m0, 0) MISSUE(m1, 1) MISSUE(m2, 2)
    LDUT(u0, 0)

    float psum = 0.f;
    f32x4 acc[2][4];
#pragma unroll
    for (int g = 0; g < 2; ++g)
#pragma unroll
        for (int n = 0; n < 4; ++n) acc[g][n] = (f32x4){0.f, 0.f, 0.f, 0.f};

    PCOMP(m0, 0)
    BAR

    for (int o = 0; o < 5; ++o) {
        const int tb = o * 6;
        PHASE(u0, u1, m1, m0, tb + 0)
        PHASE(u1, u0, m2, m1, tb + 1)
        PHASE(u0, u1, m0, m2, tb + 2)
        PHASE(u1, u0, m1, m0, tb + 3)
        PHASE(u0, u1, m2, m1, tb + 4)
        PHASE(u1, u0, m0, m2, tb + 5)
    }
    PHASE(u0, u1, m1, m0, 30)
    PHASE(u1, u0, m2, m1, 31)

    psums[prow][pjc] = psum;
    __syncthreads();
    if (t < 32) {
        float s = 0.f;
#pragma unroll
        for (int q = 0; q < 4; ++q) {
            float4 p4 = *(const float4*)&psums[t][q * 4];
            s += p4.x + p4.y + p4.z + p4.w;
        }
        rinvs[t] = 1.0f / s;
    }
    __syncthreads();
#pragma unroll
    for (int g = 0; g < 2; ++g) {
#pragma unroll
        for (int r = 0; r < 4; ++r) {
            const int irow = 16 * g + lg * 4 + r;
            const float rv = rinvs[irow];
            float* orow = out + ((size_t)(b * C_ + i0 + irow)) * DIM_ + w * 64;
#pragma unroll
            for (int n = 0; n < 4; ++n)
                orow[16 * n + lr] = acc[g][n][r] * rv + bcbo[w * 64 + 16 * n + lr];
        }
    }
}

extern "C" void kernel_launch(void* const* d_in, const int* in_sizes, int n_in,
                              void* d_out, int out_size, void* d_ws, size_t ws_size,
                              hipStream_t stream) {
    const float* features = (const float*)d_in[0];
    const float* mask     = (const float*)d_in[1];
    const float* W_w      = (const float*)d_in[2];
    const float* b_w      = (const float*)d_in[3];
    const float* a_score  = (const float*)d_in[4];
    const float* b_score  = (const float*)d_in[5];
    const float* W_out    = (const float*)d_in[6];
    const float* b_out    = (const float*)d_in[7];
    float* out = (float*)d_out;
    char* wsb  = (char*)d_ws;
    float* wsf = (float*)(wsb + FP_OFF);

    k_prep_wqk<<<128, 256, 0, stream>>>(W_w, a_score, wsf);
    k_prep_cqk<<<1, 512, 0, stream>>>(b_w, a_score, b_score, wsf);
    k_wt<<<256, 256, 0, stream>>>(W_w, W_out, b_w, wsb, wsf);
    k_sqsk<<<4096, 256, 0, stream>>>(features, wsf);
    k_ut<<<512, 256, 0, stream>>>(features, wsb);
    k_attn<<<512, 512, 0, stream>>>(mask, b_out, wsb, out);
}

// Round 12
// 136.677 us; speedup vs baseline: 2.7798x; 2.7798x over previous
//
#include <hip/hip_runtime.h>
#include <hip/hip_bf16.h>

#define B_ 8
#define C_ 2048
#define DIM_ 512
#define NEG_SLOPE 0.01f

typedef short bf16x8 __attribute__((ext_vector_type(8)));
typedef short bf16x4 __attribute__((ext_vector_type(4)));
typedef float f32x4 __attribute__((ext_vector_type(4)));

// ---- workspace byte offsets
#define WT_OFF   0                        // bf16 Wt[512][512] (W_comb^T)
#define UT_OFF   524288                   // bf16 Ut[8*512][2048]  (U^T per batch)
#define FP_OFF   (524288 + 16777216)      // fp32 region
// ---- float offsets inside fp32 region
#define BCOMB_F  0
#define WQ_F     512
#define WK_F     1024
#define CQB_F    1536
#define CK_F     1537
#define SQP_F    2048
#define SKP_F    18432

static __device__ __forceinline__ unsigned short bf16u(float x) {
    union { __hip_bfloat16 h; unsigned short u; } c;
    c.h = __float2bfloat16(x);
    return c.u;
}

// -------- merged prep: Wt + bcomb (all blocks), wqk (blocks 128..255), cqk (block 0)
__global__ __launch_bounds__(256) void k_prep(const float* __restrict__ W_w,
                                              const float* __restrict__ W_out,
                                              const float* __restrict__ b_w,
                                              const float* __restrict__ a_score,
                                              const float* __restrict__ b_score,
                                              char* wsb, float* wsf) {
    __shared__ float As[32][34];
    __shared__ float Bs[32][34];
    __shared__ float s1[256], s2[256];
    const int t = threadIdx.x;
    const int bid = blockIdx.x;

    if (bid == 0) {   // cqb = b_q.a[:512] + b_score ; ck = b_k.a[512:]
        s1[t] = b_w[t] * a_score[t] + b_w[t + 256] * a_score[t + 256];
        s2[t] = b_w[512 + t] * a_score[512 + t] + b_w[768 + t] * a_score[768 + t];
        __syncthreads();
        for (int off = 128; off > 0; off >>= 1) {
            if (t < off) { s1[t] += s1[t + off]; s2[t] += s2[t + off]; }
            __syncthreads();
        }
        if (t == 0) { wsf[CQB_F] = s1[0] + b_score[0]; wsf[CK_F] = s2[0]; }
        __syncthreads();
    }

    if (bid >= 128) {   // wq_vec / wk_vec: 4 e-rows per block, 1 per wave
        int wave = t >> 6, lane = t & 63;
        int e = (bid - 128) * 4 + wave;
        const float4* R4 = (const float4*)(W_w + (size_t)e * 1536);
        const float4* A4 = (const float4*)a_score;
        float aq = 0.f, ak = 0.f;
#pragma unroll
        for (int k = 0; k < 2; ++k) {
            float4 f = R4[lane + 64 * k];
            float4 a = A4[lane + 64 * k];
            aq += f.x * a.x + f.y * a.y + f.z * a.z + f.w * a.w;
            float4 g = R4[128 + lane + 64 * k];
            float4 a2 = A4[128 + lane + 64 * k];
            ak += g.x * a2.x + g.y * a2.y + g.z * a2.z + g.w * a2.w;
        }
#pragma unroll
        for (int off = 32; off; off >>= 1) { aq += __shfl_xor(aq, off); ak += __shfl_xor(ak, off); }
        if (lane == 0) { wsf[WQ_F + e] = aq; wsf[WK_F + e] = ak; }
    }

    // Wt[d][e] = sum_h W_w[e,1024+h]*W_out[h,d]; bcomb via e0==0 blocks
    const int d0 = (bid & 15) * 32;
    const int e0 = (bid >> 4) * 32;
    const int ty = t >> 4, tx = t & 15;
    const int hl = t >> 5, c = t & 31;
    float a00 = 0.f, a01 = 0.f, a10 = 0.f, a11 = 0.f;
    float bc = 0.f;
    for (int k0 = 0; k0 < 512; k0 += 32) {
#pragma unroll
        for (int r = 0; r < 4; ++r) {
            int h = hl + 8 * r;
            As[h][c] = W_out[(size_t)(k0 + h) * 512 + d0 + c];
            Bs[c][h] = W_w[(size_t)(e0 + h) * 1536 + 1024 + k0 + c];
        }
        __syncthreads();
        if (e0 == 0 && t < 32) {
#pragma unroll
            for (int kk = 0; kk < 32; ++kk)
                bc = fmaf(b_w[1024 + k0 + kk], As[kk][t], bc);
        }
#pragma unroll
        for (int kk = 0; kk < 32; ++kk) {
            float2 a2 = *(const float2*)&As[kk][ty * 2];
            float2 b2 = *(const float2*)&Bs[kk][tx * 2];
            a00 = fmaf(a2.x, b2.x, a00);
            a01 = fmaf(a2.x, b2.y, a01);
            a10 = fmaf(a2.y, b2.x, a10);
            a11 = fmaf(a2.y, b2.y, a11);
        }
        __syncthreads();
    }
    unsigned short* Wt = (unsigned short*)(wsb + WT_OFF);
    const int d = d0 + ty * 2, e = e0 + tx * 2;
    Wt[(size_t)d * 512 + e]           = bf16u(a00);
    Wt[(size_t)d * 512 + e + 1]       = bf16u(a01);
    Wt[(size_t)(d + 1) * 512 + e]     = bf16u(a10);
    Wt[(size_t)(d + 1) * 512 + e + 1] = bf16u(a11);
    if (e0 == 0 && t < 32) wsf[BCOMB_F + d0 + t] = bc;
}

// -------- Ut + fused sq'/sk' --------
// Ut[b,d,j] = sum_e Wt[d,e] * F[b,j,e]  (512 blocks: j-tile 32, 4 waves x 128 d)
// Also: sq'[n], sk'[n] for this block's 32 rows (fp32 F, same math as old k_sqsk).
__global__ __launch_bounds__(256) void k_ut(const float* __restrict__ F,
                                            char* __restrict__ wsb, float* __restrict__ wsf) {
    __shared__ unsigned short Fb[32][520];
    const int t = threadIdx.x;
    const int bid = blockIdx.x;
    const int b = bid & 7, j0 = (bid >> 3) * 32;
    const unsigned short* Wt = (const unsigned short*)(wsb + WT_OFF);
    unsigned short* Ut = (unsigned short*)(wsb + UT_OFF) + (size_t)b * 512 * 2048;
    const float* Ft = F + ((size_t)(b * C_ + j0)) * 512;

    {   // sq'/sk' for rows j0..j0+31: thread t -> row t>>3, e-chunk (t&7)
        const int r = t >> 3, g = t & 7;
        const float4* Fr = (const float4*)(F + ((size_t)(b * C_ + j0 + r)) * 512);
        const float4* WQ4 = (const float4*)(wsf + WQ_F);
        const float4* WK4 = (const float4*)(wsf + WK_F);
        float aq = 0.f, ak = 0.f;
#pragma unroll
        for (int cc = 0; cc < 16; ++cc) {
            float4 f = Fr[cc * 8 + g];
            float4 q = WQ4[cc * 8 + g];
            float4 kk = WK4[cc * 8 + g];
            aq += f.x * q.x + f.y * q.y + f.z * q.z + f.w * q.w;
            ak += f.x * kk.x + f.y * kk.y + f.z * kk.z + f.w * kk.w;
        }
        aq += __shfl_xor(aq, 1); aq += __shfl_xor(aq, 2); aq += __shfl_xor(aq, 4);
        ak += __shfl_xor(ak, 1); ak += __shfl_xor(ak, 2); ak += __shfl_xor(ak, 4);
        if (g == 0) {
            wsf[SQP_F + b * C_ + j0 + r] = aq + wsf[CQB_F];
            wsf[SKP_F + b * C_ + j0 + r] = ak + wsf[CK_F];
        }
    }

#pragma unroll
    for (int q = 0; q < 16; ++q) {
        float4 v = *(const float4*)(Ft + (size_t)q * 1024 + t * 4);
        int jr = 2 * q + (t >> 7);
        int e = (t & 127) * 4;
        unsigned int lo = (unsigned int)bf16u(v.x) | ((unsigned int)bf16u(v.y) << 16);
        unsigned int hi = (unsigned int)bf16u(v.z) | ((unsigned int)bf16u(v.w) << 16);
        *(uint2*)&Fb[jr][e] = make_uint2(lo, hi);
    }
    __syncthreads();
    const int l = t & 63, lr = l & 15, lg = l >> 4;
    const int d0 = (t >> 6) * 128;
    f32x4 acc[8][2];
#pragma unroll
    for (int m = 0; m < 8; ++m)
#pragma unroll
        for (int n = 0; n < 2; ++n) acc[m][n] = (f32x4){0.f, 0.f, 0.f, 0.f};
#pragma unroll
    for (int ks = 0; ks < 16; ++ks) {
        bf16x8 af[8], bv[2];
#pragma unroll
        for (int m = 0; m < 8; ++m)
            af[m] = *(const bf16x8*)(Wt + (size_t)(d0 + 16 * m + lr) * 512 + ks * 32 + 8 * lg);
#pragma unroll
        for (int n = 0; n < 2; ++n)
            bv[n] = *(const bf16x8*)&Fb[16 * n + lr][ks * 32 + 8 * lg];
#pragma unroll
        for (int m = 0; m < 8; ++m)
#pragma unroll
            for (int n = 0; n < 2; ++n)
                acc[m][n] = __builtin_amdgcn_mfma_f32_16x16x32_bf16(af[m], bv[n], acc[m][n], 0, 0, 0);
    }
#pragma unroll
    for (int m = 0; m < 8; ++m)
#pragma unroll
        for (int n = 0; n < 2; ++n)
#pragma unroll
            for (int r = 0; r < 4; ++r) {
                int d = d0 + 16 * m + lg * 4 + r;
                int j = j0 + 16 * n + lr;
                Ut[(size_t)d * 2048 + j] = bf16u(acc[m][n][r]);
            }
}

// -------- fused attention (identical to R10's 76.7us version) --------
#define BAR asm volatile("s_waitcnt lgkmcnt(0)\n\ts_barrier" ::: "memory");
#define SCHEDB __builtin_amdgcn_sched_barrier(0);

#define MISSUE(M, KT) { \
    M = __builtin_nontemporal_load((const f32x4*)(mrow + (size_t)(KT) * 64)); }

#define PCX(KV, MV, I) { \
    float z = sqv + (KV); z = fmaxf(z, z * NEG_SLOPE) * (MV); \
    z = __expf(z); psum += z; vv[I] = (short)bf16u(z); }

#define PCOMP(M, KT) { \
    const int kt = (KT); \
    float4 ka = *(const float4*)&sk_lds[kt * 64 + pjc * 4]; \
    bf16x4 vv; \
    PCX(ka.x, M[0], 0) PCX(ka.y, M[1], 1) PCX(ka.z, M[2], 2) PCX(ka.w, M[3], 3) \
    *(bf16x4*)(Pbyte + (kt & 1) * 8192 + prow * 128 \
               + (((pjc >> 1) ^ (prow & 7)) << 4) + ((pjc & 1) << 3)) = vv; }

#define LDUT(U, KT) { \
    const int kt = (KT); \
    _Pragma("unroll") \
    for (int n = 0; n < 2; ++n) { \
        const unsigned short* up = Utw + (size_t)(16 * n + lr) * 2048 + kt * 64 + 8 * lg; \
        U[2 * n]     = *(const bf16x8*)up; \
        U[2 * n + 1] = *(const bf16x8*)(up + 32); \
    } }

#define MFMAP(U, KP) { \
    const char* pb = Pbyte + ((KP) & 1) * 8192; \
    _Pragma("unroll") \
    for (int g = 0; g < 4; ++g) { \
        const char* rp = pb + (16 * g + lr) * 128; \
        bf16x8 a0 = *(const bf16x8*)(rp + ((lg ^ (lr & 7)) << 4)); \
        bf16x8 a1 = *(const bf16x8*)(rp + (((4 + lg) ^ (lr & 7)) << 4)); \
        _Pragma("unroll") \
        for (int n = 0; n < 2; ++n) { \
            acc[g][n] = __builtin_amdgcn_mfma_f32_16x16x32_bf16(a0, U[2 * n],     acc[g][n], 0, 0, 0); \
            acc[g][n] = __builtin_amdgcn_mfma_f32_16x16x32_bf16(a1, U[2 * n + 1], acc[g][n], 0, 0, 0); \
        } \
    } }

#define PHASE(UC, UN, MC, MI, KP) { \
    const int kp = (KP); \
    if (kp + 1 < 32) { PCOMP(MC, kp + 1) LDUT(UN, kp + 1) } \
    SCHEDB \
    if (kp + 3 < 32) MISSUE(MI, kp + 3) \
    SCHEDB \
    MFMAP(UC, kp) \
    BAR }

__global__ __launch_bounds__(1024, 1) void k_attn(const float* __restrict__ mask,
                                                  const float* __restrict__ b_out,
                                                  char* __restrict__ wsb,
                                                  float* __restrict__ out) {
    __shared__ unsigned short Pt[2][64][64];
    __shared__ float sk_lds[2048];
    __shared__ float bcbo[512];
    __shared__ float psums[64][16];
    __shared__ float rinvs[64];
    const int t = threadIdx.x;
    const int bid = blockIdx.x;
    const int b = bid & 7, i0 = (bid >> 3) * 64;      // b -> XCD; Ut[b] L2-resident
    const int w = t >> 6, l = t & 63, lr = l & 15, lg = l >> 4;
    const int prow = t >> 4, pjc = t & 15;            // P-compute coords
    const float* wsf = (const float*)(wsb + FP_OFF);
    const unsigned short* Utw = (const unsigned short*)(wsb + UT_OFF)
                                + (size_t)b * 512 * 2048 + (size_t)(w * 32) * 2048;
    char* Pbyte = (char*)Pt;
    const float sqv = wsf[SQP_F + b * C_ + i0 + prow];
    const float* mrow = mask + ((size_t)(b * C_ + i0 + prow)) * C_ + pjc * 4;

    if (t < 512) {   // stage sk row + fused bias
        const float* skp = wsf + SKP_F + b * C_;
        *(float4*)&sk_lds[t * 4] = *(const float4*)(skp + t * 4);
        bcbo[t & 511] = wsf[BCOMB_F + (t & 511)] + b_out[t & 511];
    }
    __syncthreads();

    f32x4 m0, m1, m2;
    bf16x8 u0[4], u1[4];
    MISSUE(m0, 0) MISSUE(m1, 1) MISSUE(m2, 2)
    LDUT(u0, 0)

    float psum = 0.f;
    f32x4 acc[4][2];
#pragma unroll
    for (int g = 0; g < 4; ++g)
#pragma unroll
        for (int n = 0; n < 2; ++n) acc[g][n] = (f32x4){0.f, 0.f, 0.f, 0.f};

    PCOMP(m0, 0)
    BAR

    for (int o = 0; o < 5; ++o) {
        const int tb = o * 6;
        PHASE(u0, u1, m1, m0, tb + 0)
        PHASE(u1, u0, m2, m1, tb + 1)
        PHASE(u0, u1, m0, m2, tb + 2)
        PHASE(u1, u0, m1, m0, tb + 3)
        PHASE(u0, u1, m2, m1, tb + 4)
        PHASE(u1, u0, m0, m2, tb + 5)
    }
    PHASE(u0, u1, m1, m0, 30)
    PHASE(u1, u0, m2, m1, 31)

    psums[prow][pjc] = psum;
    __syncthreads();
    if (t < 64) {
        float s = 0.f;
#pragma unroll
        for (int q = 0; q < 4; ++q) {
            float4 p4 = *(const float4*)&psums[t][q * 4];
            s += p4.x + p4.y + p4.z + p4.w;
        }
        rinvs[t] = 1.0f / s;
    }
    __syncthreads();
#pragma unroll
    for (int g = 0; g < 4; ++g) {
#pragma unroll
        for (int r = 0; r < 4; ++r) {
            const int irow = 16 * g + lg * 4 + r;
            const float rv = rinvs[irow];
            float* orow = out + ((size_t)(b * C_ + i0 + irow)) * DIM_ + w * 32;
#pragma unroll
            for (int n = 0; n < 2; ++n)
                orow[16 * n + lr] = acc[g][n][r] * rv + bcbo[w * 32 + 16 * n + lr];
        }
    }
}

extern "C" void kernel_launch(void* const* d_in, const int* in_sizes, int n_in,
                              void* d_out, int out_size, void* d_ws, size_t ws_size,
                              hipStream_t stream) {
    const float* features = (const float*)d_in[0];
    const float* mask     = (const float*)d_in[1];
    const float* W_w      = (const float*)d_in[2];
    const float* b_w      = (const float*)d_in[3];
    const float* a_score  = (const float*)d_in[4];
    const float* b_score  = (const float*)d_in[5];
    const float* W_out    = (const float*)d_in[6];
    const float* b_out    = (const float*)d_in[7];
    float* out = (float*)d_out;
    char* wsb  = (char*)d_ws;
    float* wsf = (float*)(wsb + FP_OFF);

    k_prep<<<256, 256, 0, stream>>>(W_w, W_out, b_w, a_score, b_score, wsb, wsf);
    k_ut<<<512, 256, 0, stream>>>(features, wsb, wsf);
    k_attn<<<256, 1024, 0, stream>>>(mask, b_out, wsb, out);
}